// Round 1
// baseline (574.869 us; speedup 1.0000x reference)
//
#include <hip/hip_runtime.h>

typedef unsigned int  u32;
typedef unsigned short u16;
typedef __attribute__((ext_vector_type(8))) short short8;
typedef __attribute__((ext_vector_type(4))) float f32x4;

#define CI 64
#define CO 128
#define HH 128
#define WW 128
#define HO 126
#define WO 126

// round-to-nearest-even fp32 -> bf16 (bits)
__device__ __forceinline__ u16 f2bf(float f) {
    u32 u = __builtin_bit_cast(u32, f);
    u = (u + 0x7FFFu + ((u >> 16) & 1u)) >> 16;
    return (u16)u;
}

// ---- kernel 1: reorder weights (C_out,C_in,3,3) fp32 -> [tap][co][ci] bf16 in ws ----
__global__ void reorder_w(const float* __restrict__ w, u16* __restrict__ wq) {
    int i = blockIdx.x * 256 + threadIdx.x;     // i over 9*128*64 = 73728
    if (i < 9 * CO * CI) {
        int ci  = i & 63;
        int co  = (i >> 6) & 127;
        int tap = i >> 13;
        wq[i] = f2bf(w[(co * CI + ci) * 9 + tap]);
    }
}

// ---- kernel 2: fused conv(implicit GEMM, bf16 MFMA) + bias + mish + BN affine ----
// block: (h_out, n); 256 threads = 4 waves; tile 128co x 128w (w 126..127 masked)
__global__ __launch_bounds__(256, 2)
void conv_mfma(const float* __restrict__ x, const u16* __restrict__ wq,
               const float* __restrict__ bias, const float* __restrict__ gamma,
               const float* __restrict__ beta, const float* __restrict__ rmean,
               const float* __restrict__ rvar, float* __restrict__ out) {
    // input tile, bf16, layout [kh][w(130)][ci(64)] with ci-group XOR swizzle.
    // row stride = 64 bf16 = 32 dwords; group g (8 ci = 16B) stored at (g ^ (w&7)).
    __shared__ u32 in_lds[3 * 130 * 32];
    __shared__ float s_scale[CO], s_shift[CO], s_bias[CO];

    const int tid = threadIdx.x;
    const int h0  = blockIdx.x;       // 0..125
    const int n   = blockIdx.y;       // 0..31

    // per-channel BN params
    if (tid < CO) {
        float sc = gamma[tid] * rsqrtf(rvar[tid] + 1e-5f);
        s_scale[tid] = sc;
        s_shift[tid] = beta[tid] - rmean[tid] * sc;
        s_bias[tid]  = bias[tid];
    }
    // zero-fill pad columns w=128,129 (read by masked-out lanes only)
    if (tid < 48) {
        int kh  = tid >> 4;
        int rem = tid & 15;
        int w   = 128 + (rem & 1);
        int g   = rem >> 1;
        uint4 z = {0u, 0u, 0u, 0u};
        *(uint4*)&in_lds[(kh * 130 + w) * 32 + ((g ^ (w & 7)) * 4)] = z;
    }
    // stage input: 3 rows x 64ci x 128w fp32 -> bf16, transposed into LDS.
    // thread gathers 8 ci (one 16B group) for one w: global reads are
    // wave-coalesced (lanes = consecutive w), LDS write is ds_write_b128.
    const float* xb = x + (size_t)n * CI * HH * WW;
    for (int it = 0; it < 12; ++it) {
        int idx = it * 256 + tid;            // 3*8*128 = 3072 total
        int w   = idx & 127;
        int g   = (idx >> 7) & 7;
        int kh  = idx >> 10;
        const float* p = xb + (g * 8) * (HH * WW) + (h0 + kh) * WW + w;
        float v[8];
#pragma unroll
        for (int j = 0; j < 8; ++j) v[j] = p[j * (HH * WW)];
        uint4 q;
        q.x = (u32)f2bf(v[0]) | ((u32)f2bf(v[1]) << 16);
        q.y = (u32)f2bf(v[2]) | ((u32)f2bf(v[3]) << 16);
        q.z = (u32)f2bf(v[4]) | ((u32)f2bf(v[5]) << 16);
        q.w = (u32)f2bf(v[6]) | ((u32)f2bf(v[7]) << 16);
        *(uint4*)&in_lds[(kh * 130 + w) * 32 + ((g ^ (w & 7)) * 4)] = q;
    }
    __syncthreads();

    const int wv = tid >> 6;
    const int li = tid & 15;          // lane & 15
    const int qd = (tid & 63) >> 4;   // quad
    const int wm = wv & 1;            // m-half (c_out)
    const int wn = wv >> 1;           // n-half (pixels)

    f32x4 zero4 = {0.f, 0.f, 0.f, 0.f};
    f32x4 acc[4][4];
#pragma unroll
    for (int i = 0; i < 4; ++i)
#pragma unroll
        for (int j = 0; j < 4; ++j) acc[i][j] = zero4;

    const uint4* wg = (const uint4*)wq;   // [tap][co][g] 16B granules

    // barrier-free K-loop: 9 taps x 2 K-steps of 32
#pragma unroll 1
    for (int kh = 0; kh < 3; ++kh) {
#pragma unroll
        for (int kw = 0; kw < 3; ++kw) {
            const int tap = kh * 3 + kw;
#pragma unroll
            for (int ks = 0; ks < 2; ++ks) {
                short8 a[4], b[4];
#pragma unroll
                for (int i = 0; i < 4; ++i) {
                    int co = wm * 64 + i * 16 + li;
                    a[i] = __builtin_bit_cast(short8,
                        wg[tap * 1024 + co * 8 + ks * 4 + qd]);   // A[m=co][k] from L1/L2
                }
#pragma unroll
                for (int j = 0; j < 4; ++j) {
                    int w = wn * 64 + j * 16 + li + kw;           // input col
                    int g = ks * 4 + qd;                          // ci group
                    b[j] = *(const short8*)&in_lds[(kh * 130 + w) * 32 +
                                                   ((g ^ (w & 7)) * 4)];
                }
#pragma unroll
                for (int i = 0; i < 4; ++i)
#pragma unroll
                    for (int j = 0; j < 4; ++j)
                        acc[i][j] = __builtin_amdgcn_mfma_f32_16x16x32_bf16(
                            a[i], b[j], acc[i][j], 0, 0, 0);
            }
        }
    }

    // epilogue: bias + mish + BN affine, coalesced stores (lanes = consecutive w)
    float* ob = out + (size_t)n * CO * (HO * WO) + (size_t)h0 * WO;
#pragma unroll
    for (int j = 0; j < 4; ++j) {
        int wo = wn * 64 + j * 16 + li;
        if (wo < WO) {
#pragma unroll
            for (int i = 0; i < 4; ++i) {
#pragma unroll
                for (int r = 0; r < 4; ++r) {
                    int co  = wm * 64 + i * 16 + qd * 4 + r;      // C/D row = quad*4+reg
                    float z = acc[i][j][r] + s_bias[co];
                    float zc = fminf(z, 20.0f);
                    float u  = 1.0f + __expf(zc);
                    float u2 = u * u;
                    float t  = (u2 - 1.0f) / (u2 + 1.0f);          // tanh(softplus(z))
                    ob[(size_t)co * (HO * WO) + wo] = z * t * s_scale[co] + s_shift[co];
                }
            }
        }
    }
}

extern "C" void kernel_launch(void* const* d_in, const int* in_sizes, int n_in,
                              void* d_out, int out_size, void* d_ws, size_t ws_size,
                              hipStream_t stream) {
    const float* x     = (const float*)d_in[0];
    const float* wt    = (const float*)d_in[1];
    const float* bias  = (const float*)d_in[2];
    const float* gamma = (const float*)d_in[3];
    const float* beta  = (const float*)d_in[4];
    const float* rmean = (const float*)d_in[5];
    const float* rvar  = (const float*)d_in[6];
    u16* wq = (u16*)d_ws;                       // 147456 B of ws used

    hipLaunchKernelGGL(reorder_w, dim3(288), dim3(256), 0, stream, wt, wq);
    hipLaunchKernelGGL(conv_mfma, dim3(HO, 32), dim3(256), 0, stream,
                       x, wq, bias, gamma, beta, rmean, rvar, (float*)d_out);
}

// Round 2
// 569.805 us; speedup vs baseline: 1.0089x; 1.0089x over previous
//
#include <hip/hip_runtime.h>

typedef unsigned int  u32;
typedef unsigned short u16;
typedef __attribute__((ext_vector_type(8))) short short8;
typedef __attribute__((ext_vector_type(4))) float f32x4;

#define CI 64
#define CO 128
#define HH 128
#define WW 128
#define HO 126
#define WO 126

// round-to-nearest-even fp32 -> bf16 (bits)
__device__ __forceinline__ u16 f2bf(float f) {
    u32 u = __builtin_bit_cast(u32, f);
    u = (u + 0x7FFFu + ((u >> 16) & 1u)) >> 16;
    return (u16)u;
}

// ---- kernel 1: reorder weights (C_out,C_in,3,3) fp32 -> [tap][co][ci] bf16 ----
__global__ void reorder_w(const float* __restrict__ w, u16* __restrict__ wq) {
    int i = blockIdx.x * 256 + threadIdx.x;     // 9*128*64 = 73728
    if (i < 9 * CO * CI) {
        int ci  = i & 63;
        int co  = (i >> 6) & 127;
        int tap = i >> 13;
        wq[i] = f2bf(w[(co * CI + ci) * 9 + tap]);
    }
}

// ---- kernel 2 (fast path): x fp32 NCHW -> bf16 swizzled-NHWC in ws ----
// layout: xq[(n*128+h)*8192 + w*64 + slot*8 + j] holds ci = (slot^(w&7))*8 + j
// => conv can DMA rows h0..h0+2 as one contiguous 48 KB block, and the XOR
//    swizzle makes the later ds_read_b128 B-fragment reads bank-conflict-free.
__global__ __launch_bounds__(256)
void prep_x(const float* __restrict__ x, u16* __restrict__ xq) {
    const int row = blockIdx.x;            // n*128 + h, 4096 rows
    const int n = row >> 7, h = row & 127;
    const float* xb = x + (size_t)n * CI * HH * WW + (size_t)h * WW;
    u16* dst = xq + (size_t)row * 8192;
    for (int it = 0; it < 4; ++it) {
        int idx  = it * 256 + threadIdx.x; // 1024 = 128 w * 8 slots
        int slot = idx & 7;
        int w    = idx >> 3;
        int g    = slot ^ (w & 7);
        const float* p = xb + (g * 8) * (HH * WW) + w;
        float v[8];
#pragma unroll
        for (int j = 0; j < 8; ++j) v[j] = p[j * (HH * WW)];
        uint4 q;
        q.x = (u32)f2bf(v[0]) | ((u32)f2bf(v[1]) << 16);
        q.y = (u32)f2bf(v[2]) | ((u32)f2bf(v[3]) << 16);
        q.z = (u32)f2bf(v[4]) | ((u32)f2bf(v[5]) << 16);
        q.w = (u32)f2bf(v[6]) | ((u32)f2bf(v[7]) << 16);
        *(uint4*)(dst + (size_t)w * 64 + slot * 8) = q;   // coalesced: tid-contiguous 16B
    }
}

// ---- kernel 3 (fast path): conv via implicit GEMM, DMA staging ----
__global__ __launch_bounds__(256, 2)
void conv_mfma_v2(const u16* __restrict__ xq, const u16* __restrict__ wq,
                  const float* __restrict__ bias, const float* __restrict__ gamma,
                  const float* __restrict__ beta, const float* __restrict__ rmean,
                  const float* __restrict__ rvar, float* __restrict__ out) {
    __shared__ u16 in_lds[3 * 128 * 64];   // 48 KB, [kh][w][slot*8+j], swizzled layout
    __shared__ float s_scale[CO], s_shift[CO], s_bias[CO];

    const int tid = threadIdx.x;
    const int h0  = blockIdx.x;       // 0..125
    const int n   = blockIdx.y;       // 0..31

    if (tid < CO) {
        float sc = gamma[tid] * rsqrtf(rvar[tid] + 1e-5f);
        s_scale[tid] = sc;
        s_shift[tid] = beta[tid] - rmean[tid] * sc;
        s_bias[tid]  = bias[tid];
    }

    // DMA rows h0..h0+2 (contiguous 48 KB in xq) into LDS: 12 x 1KB per wave.
    const int wv   = tid >> 6;
    const int lane = tid & 63;
    const u16* src = xq + (size_t)(n * 128 + h0) * 8192;
#pragma unroll
    for (int s = 0; s < 12; ++s) {
        int chunk = s * 4 + wv;                      // 48 chunks of 512 u16 (1 KB)
        const u16* gp = src + chunk * 512 + lane * 8;
        u16*       lp = in_lds + chunk * 512 + lane * 8;
        __builtin_amdgcn_global_load_lds(
            (const __attribute__((address_space(1))) u32*)gp,
            (__attribute__((address_space(3))) u32*)lp, 16, 0, 0);
    }
    __syncthreads();

    const int li = tid & 15;          // lane & 15
    const int qd = (tid & 63) >> 4;   // quad
    const int wm = wv & 1;            // m-half (c_out)
    const int wn = wv >> 1;           // n-half (pixels)

    f32x4 zero4 = {0.f, 0.f, 0.f, 0.f};
    f32x4 acc[4][4];
#pragma unroll
    for (int i = 0; i < 4; ++i)
#pragma unroll
        for (int j = 0; j < 4; ++j) acc[i][j] = zero4;

    const uint4* wg = (const uint4*)wq;   // [tap][co][g] 16B granules

    // barrier-free K-loop: 9 taps x 2 K-steps of 32
#pragma unroll 1
    for (int kh = 0; kh < 3; ++kh) {
#pragma unroll
        for (int kw = 0; kw < 3; ++kw) {
            const int tap = kh * 3 + kw;
#pragma unroll
            for (int ks = 0; ks < 2; ++ks) {
                short8 a[4], b[4];
#pragma unroll
                for (int i = 0; i < 4; ++i) {
                    int co = wm * 64 + i * 16 + li;
                    a[i] = __builtin_bit_cast(short8,
                        wg[tap * 1024 + co * 8 + ks * 4 + qd]);   // A from L1/L2
                }
#pragma unroll
                for (int j = 0; j < 4; ++j) {
                    int w = wn * 64 + j * 16 + li + kw;           // input col (<=129; OOB lanes masked in epilogue)
                    int g = ks * 4 + qd;                          // ci group
                    b[j] = *(const short8*)&in_lds[(size_t)(kh * 128 + w) * 64 +
                                                   ((g ^ (w & 7)) * 8)];
                }
#pragma unroll
                for (int i = 0; i < 4; ++i)
#pragma unroll
                    for (int j = 0; j < 4; ++j)
                        acc[i][j] = __builtin_amdgcn_mfma_f32_16x16x32_bf16(
                            a[i], b[j], acc[i][j], 0, 0, 0);
            }
        }
    }

    // epilogue: bias + mish + BN affine
    float* ob = out + (size_t)n * CO * (HO * WO) + (size_t)h0 * WO;
#pragma unroll
    for (int j = 0; j < 4; ++j) {
        int wo = wn * 64 + j * 16 + li;
        if (wo < WO) {
#pragma unroll
            for (int i = 0; i < 4; ++i) {
#pragma unroll
                for (int r = 0; r < 4; ++r) {
                    int co  = wm * 64 + i * 16 + qd * 4 + r;      // C/D row = quad*4+reg
                    float z  = acc[i][j][r] + s_bias[co];
                    float u  = 1.0f + __expf(fminf(z, 20.0f));
                    float u2 = u * u;
                    float t  = __fdividef(u2 - 1.0f, u2 + 1.0f);  // tanh(softplus(z))
                    ob[(size_t)co * (HO * WO) + wo] = z * t * s_scale[co] + s_shift[co];
                }
            }
        }
    }
}

// ---- fallback (round-1) conv: used only if ws too small for xq ----
__global__ __launch_bounds__(256, 2)
void conv_mfma(const float* __restrict__ x, const u16* __restrict__ wq,
               const float* __restrict__ bias, const float* __restrict__ gamma,
               const float* __restrict__ beta, const float* __restrict__ rmean,
               const float* __restrict__ rvar, float* __restrict__ out) {
    __shared__ u32 in_lds[3 * 130 * 32];
    __shared__ float s_scale[CO], s_shift[CO], s_bias[CO];

    const int tid = threadIdx.x;
    const int h0  = blockIdx.x;
    const int n   = blockIdx.y;

    if (tid < CO) {
        float sc = gamma[tid] * rsqrtf(rvar[tid] + 1e-5f);
        s_scale[tid] = sc;
        s_shift[tid] = beta[tid] - rmean[tid] * sc;
        s_bias[tid]  = bias[tid];
    }
    if (tid < 48) {
        int kh  = tid >> 4;
        int rem = tid & 15;
        int w   = 128 + (rem & 1);
        int g   = rem >> 1;
        uint4 z = {0u, 0u, 0u, 0u};
        *(uint4*)&in_lds[(kh * 130 + w) * 32 + ((g ^ (w & 7)) * 4)] = z;
    }
    const float* xb = x + (size_t)n * CI * HH * WW;
    for (int it = 0; it < 12; ++it) {
        int idx = it * 256 + tid;
        int w   = idx & 127;
        int g   = (idx >> 7) & 7;
        int kh  = idx >> 10;
        const float* p = xb + (g * 8) * (HH * WW) + (h0 + kh) * WW + w;
        float v[8];
#pragma unroll
        for (int j = 0; j < 8; ++j) v[j] = p[j * (HH * WW)];
        uint4 q;
        q.x = (u32)f2bf(v[0]) | ((u32)f2bf(v[1]) << 16);
        q.y = (u32)f2bf(v[2]) | ((u32)f2bf(v[3]) << 16);
        q.z = (u32)f2bf(v[4]) | ((u32)f2bf(v[5]) << 16);
        q.w = (u32)f2bf(v[6]) | ((u32)f2bf(v[7]) << 16);
        *(uint4*)&in_lds[(kh * 130 + w) * 32 + ((g ^ (w & 7)) * 4)] = q;
    }
    __syncthreads();

    const int wv = tid >> 6;
    const int li = tid & 15;
    const int qd = (tid & 63) >> 4;
    const int wm = wv & 1;
    const int wn = wv >> 1;

    f32x4 zero4 = {0.f, 0.f, 0.f, 0.f};
    f32x4 acc[4][4];
#pragma unroll
    for (int i = 0; i < 4; ++i)
#pragma unroll
        for (int j = 0; j < 4; ++j) acc[i][j] = zero4;

    const uint4* wg = (const uint4*)wq;

#pragma unroll 1
    for (int kh = 0; kh < 3; ++kh) {
#pragma unroll
        for (int kw = 0; kw < 3; ++kw) {
            const int tap = kh * 3 + kw;
#pragma unroll
            for (int ks = 0; ks < 2; ++ks) {
                short8 a[4], b[4];
#pragma unroll
                for (int i = 0; i < 4; ++i) {
                    int co = wm * 64 + i * 16 + li;
                    a[i] = __builtin_bit_cast(short8,
                        wg[tap * 1024 + co * 8 + ks * 4 + qd]);
                }
#pragma unroll
                for (int j = 0; j < 4; ++j) {
                    int w = wn * 64 + j * 16 + li + kw;
                    int g = ks * 4 + qd;
                    b[j] = *(const short8*)&in_lds[(kh * 130 + w) * 32 +
                                                   ((g ^ (w & 7)) * 4)];
                }
#pragma unroll
                for (int i = 0; i < 4; ++i)
#pragma unroll
                    for (int j = 0; j < 4; ++j)
                        acc[i][j] = __builtin_amdgcn_mfma_f32_16x16x32_bf16(
                            a[i], b[j], acc[i][j], 0, 0, 0);
            }
        }
    }

    float* ob = out + (size_t)n * CO * (HO * WO) + (size_t)h0 * WO;
#pragma unroll
    for (int j = 0; j < 4; ++j) {
        int wo = wn * 64 + j * 16 + li;
        if (wo < WO) {
#pragma unroll
            for (int i = 0; i < 4; ++i) {
#pragma unroll
                for (int r = 0; r < 4; ++r) {
                    int co  = wm * 64 + i * 16 + qd * 4 + r;
                    float z  = acc[i][j][r] + s_bias[co];
                    float u  = 1.0f + __expf(fminf(z, 20.0f));
                    float u2 = u * u;
                    float t  = __fdividef(u2 - 1.0f, u2 + 1.0f);
                    ob[(size_t)co * (HO * WO) + wo] = z * t * s_scale[co] + s_shift[co];
                }
            }
        }
    }
}

extern "C" void kernel_launch(void* const* d_in, const int* in_sizes, int n_in,
                              void* d_out, int out_size, void* d_ws, size_t ws_size,
                              hipStream_t stream) {
    const float* x     = (const float*)d_in[0];
    const float* wt    = (const float*)d_in[1];
    const float* bias  = (const float*)d_in[2];
    const float* gamma = (const float*)d_in[3];
    const float* beta  = (const float*)d_in[4];
    const float* rmean = (const float*)d_in[5];
    const float* rvar  = (const float*)d_in[6];

    const size_t XQ_BYTES = (size_t)64 * 1024 * 1024;    // 32*128*128*64*2 = 64 MiB
    const size_t WQ_BYTES = (size_t)9 * CO * CI * 2;     // 144 KiB

    if (ws_size >= XQ_BYTES + WQ_BYTES) {
        u16* xq = (u16*)d_ws;
        u16* wq = (u16*)((char*)d_ws + XQ_BYTES);
        hipLaunchKernelGGL(reorder_w, dim3(288), dim3(256), 0, stream, wt, wq);
        hipLaunchKernelGGL(prep_x, dim3(4096), dim3(256), 0, stream, x, xq);
        hipLaunchKernelGGL(conv_mfma_v2, dim3(HO, 32), dim3(256), 0, stream,
                           xq, wq, bias, gamma, beta, rmean, rvar, (float*)d_out);
    } else {
        u16* wq = (u16*)d_ws;
        hipLaunchKernelGGL(reorder_w, dim3(288), dim3(256), 0, stream, wt, wq);
        hipLaunchKernelGGL(conv_mfma, dim3(HO, 32), dim3(256), 0, stream,
                           x, wq, bias, gamma, beta, rmean, rvar, (float*)d_out);
    }
}